// Round 3
// baseline (114.889 us; speedup 1.0000x reference)
//
#include <hip/hip_runtime.h>
#include <math.h>

#define NN 8192
#define TILE 128
#define NT 64                   // NN / TILE
#define NB (NT * (NT + 1) / 2)  // 2080 upper-triangular tile pairs

// ---------------- ws layout ----------------
// rank_tot: float[NB]   @ 0
// rank_cnt: int[NB]     @ 16384
// red:      float[NT*19]@ 32768   (per-diag-block elementwise stats)
// counter:  uint        @ 49152
//
// stat indices k:
// 0 sum_w | 1 sum_w*d^2 | 2 sum_u | 3 sum_u^2 | 4 sum_e | 5 sum_e^2
// 6 sum_u*e | 7 relu(0.01-u) | 8 relu(u-0.5) | 9 sum_p | 10 sum_p^2
// 11 sum_t | 12 sum_t^2 | 13 relu(-p) | 14 relu(p-1)
// 15 max_p | 16 min_p | 17 max_t | 18 min_t

__device__ __forceinline__ void pair_body(float ti, float pi,
                                          float tj, float pj, float wj,
                                          float& sA, float& sB, int& cnt) {
  float td = ti - tj;
  float pd = pi - pj;
  float x = fminf(fmaxf(fabsf(td), 0.1f), 1.0f);  // v_med3 with |td|
  // sign(td)*pd via sign-bit xor (td==0 excluded by the 0.05 mask)
  float spd = __uint_as_float(__float_as_uint(pd) ^
                              (__float_as_uint(td) & 0x80000000u));
  float viol = fmaxf(fmaf(0.16f, x, -spd), 0.f);  // 2*0.08*clip - sign*pd
  bool c = fabsf(td) >= 0.05f;
  float mv = c ? viol : 0.f;
  sA += mv;                 // Σ mv            (weighted by wi at the end)
  sB = fmaf(wj, mv, sB);    // Σ wj*mv
  cnt += c ? 1 : 0;
}

__global__ __launch_bounds__(128) void k_all(
    const float* __restrict__ p, const float* __restrict__ t,
    const float* __restrict__ u, const float* __restrict__ snr,
    float* __restrict__ rank_tot, int* __restrict__ rank_cnt,
    float* __restrict__ red, unsigned int* __restrict__ counter,
    float* __restrict__ out) {
  const int tid = threadIdx.x;
  const int bid = blockIdx.x;

  // decode linear upper-tri index -> (it, jc), row-major: row it has NT-it tiles
  int it = 0, base = 0;
  while (bid >= base + (NT - it)) { base += NT - it; ++it; }
  const int jc = it + (bid - base);
  const bool diag = (it == jc);

  __shared__ float4 s_tpw[TILE];
  const int gj = jc * TILE + tid;
  const float tj = t[gj], pj = p[gj];
  const float wjv = 2.f * expf(-snr[gj] * (1.f / 15.f)) + 0.5f;
  s_tpw[tid] = make_float4(tj, pj, wjv, 0.f);

  const int gi = it * TILE + tid;
  float ti, pi, wi;
  if (diag) {
    ti = tj; pi = pj; wi = wjv;
  } else {
    ti = t[gi]; pi = p[gi];
    wi = 2.f * expf(-snr[gi] * (1.f / 15.f)) + 0.5f;
  }
  __syncthreads();

  float sA = 0.f, sB = 0.f;
  int cnt = 0;
  if (diag) {
    for (int j = tid + 1; j < TILE; ++j) {
      float4 q = s_tpw[j];
      pair_body(ti, pi, q.x, q.y, q.z, sA, sB, cnt);
    }
  } else {
#pragma unroll 8
    for (int j = 0; j < TILE; ++j) {
      float4 q = s_tpw[j];
      pair_body(ti, pi, q.x, q.y, q.z, sA, sB, cnt);
    }
  }
  float tv = fmaf(wi, sA, sB);  // this thread's raw (wi+wj)-weighted total

  // block reduce tv/cnt across 2 waves
  const int lane = tid & 63, wv = tid >> 6;
  for (int o = 32; o > 0; o >>= 1) {
    tv += __shfl_down(tv, o, 64);
    cnt += __shfl_down(cnt, o, 64);
  }
  __shared__ float rtot[2];
  __shared__ int rcnt[2];
  if (lane == 0) { rtot[wv] = tv; rcnt[wv] = cnt; }

  // diagonal blocks also compute elementwise stats for their 128-row slice
  if (diag) {
    const float ui = u[gi];
    const float sm = ti * 0.95f + 0.025f;  // label smoothing
    const float d = pi - sm;
    const float e = fminf(fmaxf(fabsf(pi - ti), 0.001f), 1.0f);
    float v[19];
    v[0] = wi;            v[1] = wi * d * d;
    v[2] = ui;            v[3] = ui * ui;
    v[4] = e;             v[5] = e * e;
    v[6] = ui * e;
    v[7] = fmaxf(0.01f - ui, 0.f);
    v[8] = fmaxf(ui - 0.5f, 0.f);
    v[9] = pi;            v[10] = pi * pi;
    v[11] = ti;           v[12] = ti * ti;
    v[13] = fmaxf(-pi, 0.f);
    v[14] = fmaxf(pi - 1.f, 0.f);
    v[15] = pi; v[16] = pi; v[17] = ti; v[18] = ti;

    __shared__ float sred[2][19];
#pragma unroll
    for (int k = 0; k < 19; ++k) {
      float x = v[k];
      for (int o = 32; o > 0; o >>= 1) {
        float ox = __shfl_down(x, o, 64);
        if (k < 15) x += ox;
        else if (k == 15 || k == 17) x = fmaxf(x, ox);
        else x = fminf(x, ox);
      }
      if (lane == 0) sred[wv][k] = x;
    }
    __syncthreads();
    if (tid == 0) {
#pragma unroll
      for (int k = 0; k < 19; ++k) {
        float a = sred[0][k], b = sred[1][k];
        float x;
        if (k < 15) x = a + b;
        else if (k == 15 || k == 17) x = fmaxf(a, b);
        else x = fminf(a, b);
        red[it * 19 + k] = x;
      }
    }
  } else {
    __syncthreads();
  }

  // publish block partials, then signal completion (all global stores are tid0)
  __shared__ int is_last;
  if (tid == 0) {
    rank_tot[bid] = rtot[0] + rtot[1];
    rank_cnt[bid] = rcnt[0] + rcnt[1];
    __threadfence();  // release: partials visible before the counter bump
    unsigned int old = atomicAdd(counter, 1u);
    // counter init is either 0 (our restore) or 0xAAAAAAAA (harness poison);
    // the two candidate "last" values are in disjoint ranges.
    is_last = (old == (unsigned)(NB - 1) ||
               old == 0xAAAAAAAAu + (unsigned)(NB - 1)) ? 1 : 0;
  }
  __syncthreads();
  if (!is_last) return;
  __threadfence();  // acquire: invalidate L1 so we see all blocks' partials

  // ---- final reduction (only the last-finishing block runs this) ----
  double dt = 0.0;
  long long dc = 0;
  for (int i = tid; i < NB; i += TILE) {
    dt += (double)rank_tot[i];
    dc += (long long)rank_cnt[i];
  }
  for (int o = 32; o > 0; o >>= 1) {
    dt += __shfl_down(dt, o, 64);
    dc += __shfl_down(dc, o, 64);
  }
  __shared__ double sdt[2];
  __shared__ long long sdc[2];
  if (lane == 0) { sdt[wv] = dt; sdc[wv] = dc; }

  __shared__ double sfin[19];
  if (tid < 19) {
    const int k = tid;
    double x;
    if (k < 15) {
      x = 0.0;
      for (int b2 = 0; b2 < NT; ++b2) x += (double)red[b2 * 19 + k];
    } else if (k == 15 || k == 17) {
      x = -1e30;
      for (int b2 = 0; b2 < NT; ++b2) x = fmax(x, (double)red[b2 * 19 + k]);
    } else {
      x = 1e30;
      for (int b2 = 0; b2 < NT; ++b2) x = fmin(x, (double)red[b2 * 19 + k]);
    }
    sfin[k] = x;
  }
  __syncthreads();

  if (tid == 0) {
    const double total = sdt[0] + sdt[1];
    const long long c = sdc[0] + sdc[1];
    const double inv_n = 1.0 / (double)NN;

    double mean_w = sfin[0] * inv_n;
    double denom_w = fmax(mean_w, 1e-6);

    double mse = (sfin[1] * inv_n) / denom_w;

    double rank = 0.0;
    if (c > 0) rank = (0.5 * total / denom_w) / (double)c;

    double mean_u = sfin[2] * inv_n, mean_e = sfin[4] * inv_n;
    double mse_unc = (sfin[3] - 2.0 * sfin[6] + sfin[5]) * inv_n;
    double var_u = fmax(sfin[3] * inv_n - mean_u * mean_u, 0.0);
    double var_e = fmax(sfin[5] * inv_n - mean_e * mean_e, 0.0);
    double std_u = fmax(sqrt(var_u), 1e-6);
    double std_e = fmax(sqrt(var_e), 1e-6);
    double cov = sfin[6] * inv_n - mean_u * mean_e;
    double corr = cov / (std_u * std_e + 1e-6);
    double cl = fmax(0.5 - corr, 0.0);
    double unc_loss =
        0.5 * mse_unc + 0.3 * cl * cl + 0.2 * (fmax(-corr, 0.0) * 10.0);

    double ub_loss = 0.05 * ((sfin[7] + sfin[8]) * inv_n);

    double mean_p = sfin[9] * inv_n, mean_t = sfin[11] * inv_n;
    double mean_gap = fabs(mean_p - mean_t);
    double max_gap = fmax(1.0 - (sfin[15] + 1e-6) / (sfin[17] + 1e-6), 0.0);
    double t_range = sfin[17] - sfin[18];
    double p_range = sfin[15] - sfin[16];
    double range_pen = fmax(1.0 - (p_range + 1e-6) / (t_range + 1e-6), 0.0);
    double calib = 0.2 * mean_gap + 1.5 * max_gap + 1.0 * range_pen;

    double p_std = sqrt(fmax(sfin[10] * inv_n - mean_p * mean_p, 0.0));
    double t_std = sqrt(fmax(sfin[12] * inv_n - mean_t * mean_t, 0.0));
    double var_ratio = p_std / (t_std + 1e-8);
    double minvar = (p_std < 0.5 * t_std && t_std > 1e-4)
                        ? 2.0 * fmax(0.5 - var_ratio, 0.0)
                        : 0.0;

    double bounds_pen = 5.0 * ((sfin[13] + sfin[14]) * inv_n);

    // bucket5: eff_mse_w = 0.5*0.85 = 0.425, eff_rank_w = 0.4*1.5 = 0.6
    double tl = 0.425 * mse + 0.6 * rank + 0.35 * unc_loss + ub_loss + calib +
                minvar + bounds_pen;
    out[0] = (float)tl;
    *counter = 0u;  // restore, so the scheme works even without re-poison
  }
}

extern "C" void kernel_launch(void* const* d_in, const int* in_sizes, int n_in,
                              void* d_out, int out_size, void* d_ws,
                              size_t ws_size, hipStream_t stream) {
  const float* p = (const float*)d_in[0];
  const float* t = (const float*)d_in[1];
  const float* u = (const float*)d_in[2];
  const float* snr = (const float*)d_in[3];
  char* ws = (char*)d_ws;
  float* rank_tot = (float*)ws;                       // NB floats
  int* rank_cnt = (int*)(ws + 16384);                 // NB ints
  float* red = (float*)(ws + 32768);                  // NT*19 floats
  unsigned int* counter = (unsigned int*)(ws + 49152);

  hipLaunchKernelGGL(k_all, dim3(NB), dim3(TILE), 0, stream,
                     p, t, u, snr, rank_tot, rank_cnt, red, counter,
                     (float*)d_out);
}

// Round 4
// 82.956 us; speedup vs baseline: 1.3849x; 1.3849x over previous
//
#include <hip/hip_runtime.h>
#include <math.h>

#define NN 8192
#define BI 256            // i-rows per block (2 per thread)
#define BJ 128            // j-cols per block (LDS-staged)
#define NTI 32            // NN / BI
#define NTJ 64            // NN / BJ
#define NBLK 1056         // sum over I of (NTJ - 2I)

// ---------------- ws layout ----------------
// rank_tot: float[NBLK] @ 0
// rank_cnt: int[NBLK]   @ 8192
// red:      float[NTI*19] @ 16384
//
// stat indices k:
// 0 sum_w | 1 sum_w*d^2 | 2 sum_u | 3 sum_u^2 | 4 sum_e | 5 sum_e^2
// 6 sum_u*e | 7 relu(0.01-u) | 8 relu(u-0.5) | 9 sum_p | 10 sum_p^2
// 11 sum_t | 12 sum_t^2 | 13 relu(-p) | 14 relu(p-1)
// 15 max_p | 16 min_p | 17 max_t | 18 min_t

__device__ __forceinline__ void pair_body(float ti, float pi,
                                          float tj, float pj, float wj,
                                          float& sA, float& sB, int& cnt) {
  float td = ti - tj;
  float pd = pi - pj;
  float atd = fabsf(td);
  float x = fminf(fmaxf(atd, 0.1f), 1.0f);        // v_med3 w/ |td|
  // sign(td)*pd via sign-bit xor (td==0 excluded by the 0.05 mask)
  float spd = __uint_as_float(__float_as_uint(pd) ^
                              (__float_as_uint(td) & 0x80000000u));
  float viol = fmaxf(fmaf(0.16f, x, -spd), 0.f);  // 2*0.08*clip - sign*pd
  bool c = atd >= 0.05f;
  float mv = c ? viol : 0.f;
  sA += mv;               // Σ mv          (weighted by wi at block end)
  sB = fmaf(wj, mv, sB);  // Σ wj*mv
  cnt += c ? 1 : 0;
}

__global__ __launch_bounds__(128) void k_rank(
    const float* __restrict__ p, const float* __restrict__ t,
    const float* __restrict__ u, const float* __restrict__ snr,
    float* __restrict__ rank_tot, int* __restrict__ rank_cnt,
    float* __restrict__ red) {
  const int tid = threadIdx.x;
  const int bid = blockIdx.x;

  // decode bid -> (I, J): row I contributes (NTJ - 2I) blocks, J from 2I..63
  int I = 0, base = 0;
  while (bid >= base + (NTJ - 2 * I)) { base += NTJ - 2 * I; ++I; }
  const int J = 2 * I + (bid - base);

  // stage j-tile (one element per thread)
  __shared__ float4 s_tpw[BJ];
  const int gj = J * BJ + tid;
  {
    const float tj = t[gj], pj = p[gj];
    const float wj = 2.f * expf(-snr[gj] * (1.f / 15.f)) + 0.5f;
    s_tpw[tid] = make_float4(tj, pj, wj, 0.f);
  }

  // own two i-rows
  const int gi0 = I * BI + tid;
  const int gi1 = gi0 + 128;
  const float t0 = t[gi0], p0 = p[gi0];
  const float t1 = t[gi1], p1 = p[gi1];
  const float w0 = 2.f * expf(-snr[gi0] * (1.f / 15.f)) + 0.5f;
  const float w1 = 2.f * expf(-snr[gi1] * (1.f / 15.f)) + 0.5f;
  __syncthreads();

  float sA0 = 0.f, sB0 = 0.f, sA1 = 0.f, sB1 = 0.f;
  int cnt = 0;
  if (J >= 2 * I + 2) {          // full block: both rows vs all 128 j
#pragma unroll 8
    for (int j = 0; j < BJ; ++j) {
      float4 q = s_tpw[j];
      pair_body(t0, p0, q.x, q.y, q.z, sA0, sB0, cnt);
      pair_body(t1, p1, q.x, q.y, q.z, sA1, sB1, cnt);
    }
  } else if (J == 2 * I + 1) {   // row0 full, row1 masked j>tid
#pragma unroll 8
    for (int j = 0; j < BJ; ++j) {
      float4 q = s_tpw[j];
      pair_body(t0, p0, q.x, q.y, q.z, sA0, sB0, cnt);
    }
    for (int j = tid + 1; j < BJ; ++j) {
      float4 q = s_tpw[j];
      pair_body(t1, p1, q.x, q.y, q.z, sA1, sB1, cnt);
    }
  } else {                       // J == 2I: row0 masked j>tid, row1 none
    for (int j = tid + 1; j < BJ; ++j) {
      float4 q = s_tpw[j];
      pair_body(t0, p0, q.x, q.y, q.z, sA0, sB0, cnt);
    }
  }
  float tv = fmaf(w0, sA0, sB0) + fmaf(w1, sA1, sB1);

  // wave reduce tv/cnt (2 waves)
  const int lane = tid & 63, wv = tid >> 6;
  for (int o = 32; o > 0; o >>= 1) {
    tv += __shfl_down(tv, o, 64);
    cnt += __shfl_down(cnt, o, 64);
  }
  __shared__ float rtot[2];
  __shared__ int rcnt[2];
  if (lane == 0) { rtot[wv] = tv; rcnt[wv] = cnt; }

  // stats blocks (J == 2I, one per I; they also have the lightest pair work)
  const bool statsblk = (J == 2 * I);
  __shared__ float sred[2][19];
  if (statsblk) {
    const float u0 = u[gi0], u1 = u[gi1];
    const float sm0 = t0 * 0.95f + 0.025f, sm1 = t1 * 0.95f + 0.025f;
    const float d0 = p0 - sm0, d1 = p1 - sm1;
    const float e0 = fminf(fmaxf(fabsf(p0 - t0), 0.001f), 1.0f);
    const float e1 = fminf(fmaxf(fabsf(p1 - t1), 0.001f), 1.0f);
    float v[19];
    v[0] = w0 + w1;
    v[1] = w0 * d0 * d0 + w1 * d1 * d1;
    v[2] = u0 + u1;
    v[3] = u0 * u0 + u1 * u1;
    v[4] = e0 + e1;
    v[5] = e0 * e0 + e1 * e1;
    v[6] = u0 * e0 + u1 * e1;
    v[7] = fmaxf(0.01f - u0, 0.f) + fmaxf(0.01f - u1, 0.f);
    v[8] = fmaxf(u0 - 0.5f, 0.f) + fmaxf(u1 - 0.5f, 0.f);
    v[9] = p0 + p1;
    v[10] = p0 * p0 + p1 * p1;
    v[11] = t0 + t1;
    v[12] = t0 * t0 + t1 * t1;
    v[13] = fmaxf(-p0, 0.f) + fmaxf(-p1, 0.f);
    v[14] = fmaxf(p0 - 1.f, 0.f) + fmaxf(p1 - 1.f, 0.f);
    v[15] = fmaxf(p0, p1);
    v[16] = fminf(p0, p1);
    v[17] = fmaxf(t0, t1);
    v[18] = fminf(t0, t1);
#pragma unroll
    for (int k = 0; k < 19; ++k) {
      float x = v[k];
      for (int o = 32; o > 0; o >>= 1) {
        float ox = __shfl_down(x, o, 64);
        if (k < 15) x += ox;
        else if (k == 15 || k == 17) x = fmaxf(x, ox);
        else x = fminf(x, ox);
      }
      if (lane == 0) sred[wv][k] = x;
    }
  }
  __syncthreads();

  if (tid == 0) {
    rank_tot[bid] = rtot[0] + rtot[1];
    rank_cnt[bid] = rcnt[0] + rcnt[1];
    if (statsblk) {
#pragma unroll
      for (int k = 0; k < 19; ++k) {
        float a = sred[0][k], b = sred[1][k];
        float x;
        if (k < 15) x = a + b;
        else if (k == 15 || k == 17) x = fmaxf(a, b);
        else x = fminf(a, b);
        red[I * 19 + k] = x;
      }
    }
  }
}

__global__ __launch_bounds__(256) void k_final(
    const float* __restrict__ rank_tot, const int* __restrict__ rank_cnt,
    const float* __restrict__ red, float* __restrict__ out) {
  const int tid = threadIdx.x;
  double dt = 0.0;
  long long dc = 0;
  for (int i = tid; i < NBLK; i += 256) {
    dt += (double)rank_tot[i];
    dc += (long long)rank_cnt[i];
  }
  const int lane = tid & 63, wv = tid >> 6;
  for (int o = 32; o > 0; o >>= 1) {
    dt += __shfl_down(dt, o, 64);
    dc += __shfl_down(dc, o, 64);
  }
  __shared__ double sdt[4];
  __shared__ long long sdc[4];
  if (lane == 0) { sdt[wv] = dt; sdc[wv] = dc; }

  __shared__ double sfin[19];
  if (tid < 19) {
    const int k = tid;
    double x;
    if (k < 15) {
      x = 0.0;
      for (int b2 = 0; b2 < NTI; ++b2) x += (double)red[b2 * 19 + k];
    } else if (k == 15 || k == 17) {
      x = -1e30;
      for (int b2 = 0; b2 < NTI; ++b2) x = fmax(x, (double)red[b2 * 19 + k]);
    } else {
      x = 1e30;
      for (int b2 = 0; b2 < NTI; ++b2) x = fmin(x, (double)red[b2 * 19 + k]);
    }
    sfin[k] = x;
  }
  __syncthreads();

  if (tid == 0) {
    const double total = sdt[0] + sdt[1] + sdt[2] + sdt[3];
    const long long c = sdc[0] + sdc[1] + sdc[2] + sdc[3];
    const double inv_n = 1.0 / (double)NN;

    double mean_w = sfin[0] * inv_n;
    double denom_w = fmax(mean_w, 1e-6);

    double mse = (sfin[1] * inv_n) / denom_w;

    double rank = 0.0;
    if (c > 0) rank = (0.5 * total / denom_w) / (double)c;

    double mean_u = sfin[2] * inv_n, mean_e = sfin[4] * inv_n;
    double mse_unc = (sfin[3] - 2.0 * sfin[6] + sfin[5]) * inv_n;
    double var_u = fmax(sfin[3] * inv_n - mean_u * mean_u, 0.0);
    double var_e = fmax(sfin[5] * inv_n - mean_e * mean_e, 0.0);
    double std_u = fmax(sqrt(var_u), 1e-6);
    double std_e = fmax(sqrt(var_e), 1e-6);
    double cov = sfin[6] * inv_n - mean_u * mean_e;
    double corr = cov / (std_u * std_e + 1e-6);
    double cl = fmax(0.5 - corr, 0.0);
    double unc_loss =
        0.5 * mse_unc + 0.3 * cl * cl + 0.2 * (fmax(-corr, 0.0) * 10.0);

    double ub_loss = 0.05 * ((sfin[7] + sfin[8]) * inv_n);

    double mean_p = sfin[9] * inv_n, mean_t = sfin[11] * inv_n;
    double mean_gap = fabs(mean_p - mean_t);
    double max_gap = fmax(1.0 - (sfin[15] + 1e-6) / (sfin[17] + 1e-6), 0.0);
    double t_range = sfin[17] - sfin[18];
    double p_range = sfin[15] - sfin[16];
    double range_pen = fmax(1.0 - (p_range + 1e-6) / (t_range + 1e-6), 0.0);
    double calib = 0.2 * mean_gap + 1.5 * max_gap + 1.0 * range_pen;

    double p_std = sqrt(fmax(sfin[10] * inv_n - mean_p * mean_p, 0.0));
    double t_std = sqrt(fmax(sfin[12] * inv_n - mean_t * mean_t, 0.0));
    double var_ratio = p_std / (t_std + 1e-8);
    double minvar = (p_std < 0.5 * t_std && t_std > 1e-4)
                        ? 2.0 * fmax(0.5 - var_ratio, 0.0)
                        : 0.0;

    double bounds_pen = 5.0 * ((sfin[13] + sfin[14]) * inv_n);

    // bucket5: eff_mse_w = 0.5*0.85 = 0.425, eff_rank_w = 0.4*1.5 = 0.6
    double tl = 0.425 * mse + 0.6 * rank + 0.35 * unc_loss + ub_loss + calib +
                minvar + bounds_pen;
    out[0] = (float)tl;
  }
}

extern "C" void kernel_launch(void* const* d_in, const int* in_sizes, int n_in,
                              void* d_out, int out_size, void* d_ws,
                              size_t ws_size, hipStream_t stream) {
  const float* p = (const float*)d_in[0];
  const float* t = (const float*)d_in[1];
  const float* u = (const float*)d_in[2];
  const float* snr = (const float*)d_in[3];
  char* ws = (char*)d_ws;
  float* rank_tot = (float*)ws;            // NBLK floats
  int* rank_cnt = (int*)(ws + 8192);       // NBLK ints
  float* red = (float*)(ws + 16384);       // NTI*19 floats

  hipLaunchKernelGGL(k_rank, dim3(NBLK), dim3(128), 0, stream,
                     p, t, u, snr, rank_tot, rank_cnt, red);
  hipLaunchKernelGGL(k_final, dim3(1), dim3(256), 0, stream,
                     rank_tot, rank_cnt, red, (float*)d_out);
}